// Round 1
// baseline (726.732 us; speedup 1.0000x reference)
//
#include <hip/hip_runtime.h>
#include <hip/hip_bf16.h>

#define N_NODES 50000
#define N_EDGES 800000
#define DD 64
#define NGRAPH 64

__device__ __forceinline__ float swish_f(float v) {
    return v / (1.0f + __expf(-v));
}

// ---------------- scatter: agg[col[e]] += edge_attr[e] ----------------
// 16 lanes per edge, float4 each. tid consecutive -> coalesced edge_attr reads.
__global__ __launch_bounds__(256) void scatter_kernel(
    const float* __restrict__ edge_attr,
    const int* __restrict__ col,
    float* __restrict__ agg)
{
    const int tid = blockIdx.x * 256 + threadIdx.x;
    const int e = tid >> 4;
    const int q = (tid & 15) << 2;
    const int c = col[e];
    const float4 v = *reinterpret_cast<const float4*>(edge_attr + (size_t)e * DD + q);
    float* dst = agg + (size_t)c * DD + q;
    atomicAdd(dst + 0, v.x);
    atomicAdd(dst + 1, v.y);
    atomicAdd(dst + 2, v.z);
    atomicAdd(dst + 3, v.w);
}

// ---------------- fused 2-layer MLP ----------------
// lane = node (64 nodes/block), wave = 16-wide output chunk.
// W accesses are wave-uniform -> s_load broadcast (no LDS for weights).
__global__ __launch_bounds__(256) void mlp_kernel(
    const float* __restrict__ x,
    const float* __restrict__ agg,
    const float* __restrict__ u,
    const int* __restrict__ batch,
    const float* __restrict__ W1,
    const float* __restrict__ b1,
    const float* __restrict__ W2,
    const float* __restrict__ b2,
    float* __restrict__ out)
{
    __shared__ float sh[64][65];   // padded: bank = (lane + k) % 32, conflict-free
    const int lane = threadIdx.x & 63;
    const int j0 = __builtin_amdgcn_readfirstlane((threadIdx.x >> 6) << 4);
    const int node = blockIdx.x * 64 + lane;
    const bool valid = node < N_NODES;
    const int nc = valid ? node : (N_NODES - 1);

    float acc[16];
    #pragma unroll
    for (int j = 0; j < 16; ++j) acc[j] = b1[j0 + j];

    const float* __restrict__ row0 = x + (size_t)nc * DD;
    const float* __restrict__ row1 = agg + (size_t)nc * DD;
    const float* __restrict__ row2 = u + (size_t)batch[nc] * DD;

    #pragma unroll
    for (int s = 0; s < 3; ++s) {
        const float* __restrict__ row = (s == 0) ? row0 : (s == 1) ? row1 : row2;
        const float* __restrict__ w = W1 + (size_t)s * 64 * 64 + j0;
        for (int kk = 0; kk < 64; kk += 4) {
            const float4 v = *reinterpret_cast<const float4*>(row + kk);
            #pragma unroll
            for (int i = 0; i < 4; ++i) {
                const float iv = (i == 0) ? v.x : (i == 1) ? v.y : (i == 2) ? v.z : v.w;
                const float* __restrict__ wr = w + (size_t)(kk + i) * 64;
                #pragma unroll
                for (int j = 0; j < 16; ++j)
                    acc[j] += iv * wr[j];
            }
        }
    }

    #pragma unroll
    for (int j = 0; j < 16; ++j)
        sh[lane][j0 + j] = swish_f(acc[j]);

    __syncthreads();

    float acc2[16];
    #pragma unroll
    for (int j = 0; j < 16; ++j) acc2[j] = b2[j0 + j];
    for (int k = 0; k < 64; ++k) {
        const float hk = sh[lane][k];
        const float* __restrict__ wr = W2 + (size_t)k * 64 + j0;
        #pragma unroll
        for (int j = 0; j < 16; ++j)
            acc2[j] += hk * wr[j];
    }

    if (valid) {
        float* o = out + (size_t)node * DD + j0;
        #pragma unroll
        for (int j = 0; j < 16; j += 4) {
            float4 r;
            r.x = swish_f(acc2[j + 0]);
            r.y = swish_f(acc2[j + 1]);
            r.z = swish_f(acc2[j + 2]);
            r.w = swish_f(acc2[j + 3]);
            *reinterpret_cast<float4*>(o + j) = r;
        }
    }
}

extern "C" void kernel_launch(void* const* d_in, const int* in_sizes, int n_in,
                              void* d_out, int out_size, void* d_ws, size_t ws_size,
                              hipStream_t stream) {
    const float* x         = (const float*)d_in[0];
    const int*   ei        = (const int*)d_in[1];
    const float* edge_attr = (const float*)d_in[2];
    const float* u         = (const float*)d_in[3];
    const int*   batch     = (const int*)d_in[4];
    const float* W1        = (const float*)d_in[5];
    const float* b1        = (const float*)d_in[6];
    const float* W2        = (const float*)d_in[7];
    const float* b2        = (const float*)d_in[8];
    float* out = (float*)d_out;
    float* agg = (float*)d_ws;

    // zero the aggregation buffer every call (ws is not re-poisoned between replays)
    hipMemsetAsync(agg, 0, (size_t)N_NODES * DD * sizeof(float), stream);

    // col = edge_index[1] -> second row
    scatter_kernel<<<(N_EDGES * 16) / 256, 256, 0, stream>>>(edge_attr, ei + N_EDGES, agg);

    mlp_kernel<<<(N_NODES + 63) / 64, 256, 0, stream>>>(x, agg, u, batch, W1, b1, W2, b2, out);
}